// Round 5
// baseline (851.501 us; speedup 1.0000x reference)
//
#include <hip/hip_runtime.h>
#include <math.h>

#define N   12288
#define D   64
#define CAP 96   // max neighbors/row; Binomial(12288,0.002) mean 24.6, P(>=96) ~ 1e-30

typedef unsigned int uint4n __attribute__((ext_vector_type(4)));

__device__ __forceinline__ float wave_sum(float v) {
    #pragma unroll
    for (int m = 32; m >= 1; m >>= 1) v += __shfl_xor(v, m, 64);
    return v;
}
__device__ __forceinline__ float sigmoidf(float a) { return 1.0f / (1.0f + __expf(-a)); }

// K1: per wave-owned row: h = LL(x) (registers), q/k = LL(h) from registers,
// then stream the row's 48 KB adj slice -> compact neighbor list.
__global__ __launch_bounds__(256) void phase1_kernel(
        const float* __restrict__ x,
        const uint4n* __restrict__ adj4,
        const float* __restrict__ W,  const float* __restrict__ b,  const float* __restrict__ scale,
        const float* __restrict__ Wq, const float* __restrict__ bq, const float* __restrict__ scale_q,
        const float* __restrict__ Wk, const float* __restrict__ bk, const float* __restrict__ scale_k,
        float* __restrict__ h, float* __restrict__ qm, float* __restrict__ kmat,
        int* __restrict__ cnt, int* __restrict__ cols) {
    __shared__ float Wl [D * (D + 1)];   // +1 pad: 2-way bank alias (free)
    __shared__ float Wql[D * (D + 1)];
    __shared__ float Wkl[D * (D + 1)];
    __shared__ unsigned short scols[4][CAP];   // wave-private
    __shared__ int scnt[4];

    const int tid  = threadIdx.x;
    const int lane = tid & 63;
    const int w    = tid >> 6;
    const int row  = blockIdx.x * 4 + w;

    for (int idx = tid; idx < D * D; idx += 256) {
        int d = idx >> 6, kk = idx & 63;
        Wl [d * (D + 1) + kk] = W [idx];
        Wql[d * (D + 1) + kk] = Wq[idx];
        Wkl[d * (D + 1) + kk] = Wk[idx];
    }
    if (lane == 0) scnt[w] = 0;
    __syncthreads();

    // ---- h = lorentz_linear(x)[row], kept in registers
    float hvv;
    {
        float xv  = x[row * D + lane];
        float acc = b[lane];
        const float* wr = &Wl[lane * (D + 1)];
        #pragma unroll
        for (int kk = 0; kk < D; ++kk)
            acc = fmaf(__shfl(xv, kk, 64), wr[kk], acc);
        float h0   = __shfl(acc, 0, 64);
        float time = __expf(scale[0]) * sigmoidf(h0) + 1.1f;
        float sq   = fmaxf(wave_sum((lane == 0) ? 0.0f : acc * acc), 1e-8f);
        float r    = sqrtf((time * time - 1.0f) / sq);
        hvv = (lane == 0) ? time : acc * r;
        h[row * D + lane] = hvv;
    }

    // ---- q (negated time) and k from register h, shared shuffle broadcast
    {
        float accq = bq[lane], acck = bk[lane];
        const float* wq = &Wql[lane * (D + 1)];
        const float* wk = &Wkl[lane * (D + 1)];
        #pragma unroll
        for (int kk = 0; kk < D; ++kk) {
            float xk = __shfl(hvv, kk, 64);
            accq = fmaf(xk, wq[kk], accq);
            acck = fmaf(xk, wk[kk], acck);
        }
        {
            float h0   = __shfl(accq, 0, 64);
            float time = __expf(scale_q[0]) * sigmoidf(h0) + 1.1f;
            float sq   = fmaxf(wave_sum((lane == 0) ? 0.0f : accq * accq), 1e-8f);
            float r    = sqrtf((time * time - 1.0f) / sq);
            qm[row * D + lane] = (lane == 0) ? -time : accq * r;
        }
        {
            float h0   = __shfl(acck, 0, 64);
            float time = __expf(scale_k[0]) * sigmoidf(h0) + 1.1f;
            float sq   = fmaxf(wave_sum((lane == 0) ? 0.0f : acck * acck), 1e-8f);
            float r    = sqrtf((time * time - 1.0f) / sq);
            kmat[row * D + lane] = (lane == 0) ? time : acck * r;
        }
    }

    // ---- stream this row of adj (3072 uint4, nt loads), compact nonzero cols
    {
        const uint4n* rp = adj4 + (size_t)row * (N / 4);
        #pragma unroll 4
        for (int it = 0; it < (N / 4) / 64; ++it) {   // 48 iters, 1 KB/wave/iter coalesced
            int t = it * 64 + lane;
            uint4n v = __builtin_nontemporal_load(&rp[t]);
            if ((v.x | v.y | v.z | v.w) != 0u) {
                unsigned e[4] = {v.x, v.y, v.z, v.w};
                #pragma unroll
                for (int c = 0; c < 4; ++c) {
                    if (e[c] != 0u) {
                        int pos = atomicAdd(&scnt[w], 1);   // wave-private LDS atomic
                        if (pos < CAP) scols[w][pos] = (unsigned short)(t * 4 + c);
                    }
                }
            }
        }
        int m = scnt[w]; if (m > CAP) m = CAP;     // wave-private: no barrier needed
        if (lane == 0) cnt[row] = m;               // sole owner: no memset required
        for (int n = lane; n < m; n += 64)
            cols[row * CAP + n] = scols[w][n];
    }
}

// K2: wave per row: support = sum_j sigmoid((2+2*qm.k_j)/sc + bias) * h_j, normalize.
__global__ __launch_bounds__(256) void gather_kernel(
        const float* __restrict__ qm,
        const float* __restrict__ kmat,
        const float* __restrict__ h,
        const int* __restrict__ cnt,
        const int* __restrict__ cols,
        const float* __restrict__ att_bias_p,
        const float* __restrict__ att_scale_p,
        float* __restrict__ out) {
    int lane = threadIdx.x & 63;
    int row  = blockIdx.x * 4 + (threadIdx.x >> 6);

    float qv = qm[row * D + lane];
    int m = cnt[row];
    float bias      = att_bias_p[0];
    float inv_scale = 1.0f / att_scale_p[0];

    float acc = 0.0f;
    for (int n = 0; n < m; ++n) {
        int j = cols[row * CAP + n];               // wave-uniform broadcast
        float dot = wave_sum(qv * kmat[j * D + lane]);
        float att = sigmoidf(fmaf(2.0f + 2.0f * dot, inv_scale, bias));
        acc = fmaf(att, h[j * D + lane], acc);
    }

    float contrib = (lane == 0) ? -acc * acc : acc * acc;
    float inner   = wave_sum(contrib);
    float denorm  = sqrtf(fmaxf(fabsf(inner), 1e-8f));
    out[row * D + lane] = acc / denorm;
}

extern "C" void kernel_launch(void* const* d_in, const int* in_sizes, int n_in,
                              void* d_out, int out_size, void* d_ws, size_t ws_size,
                              hipStream_t stream) {
    const float*  x         = (const float*)d_in[0];
    const uint4n* adj       = (const uint4n*)d_in[1];
    const float*  W         = (const float*)d_in[2];
    const float*  b         = (const float*)d_in[3];
    const float*  scale     = (const float*)d_in[4];
    const float*  Wq        = (const float*)d_in[5];
    const float*  bq        = (const float*)d_in[6];
    const float*  scale_q   = (const float*)d_in[7];
    const float*  Wk        = (const float*)d_in[8];
    const float*  bk        = (const float*)d_in[9];
    const float*  scale_k   = (const float*)d_in[10];
    const float*  att_bias  = (const float*)d_in[11];
    const float*  att_scale = (const float*)d_in[12];
    float* out = (float*)d_out;

    float* h    = (float*)d_ws;                   // N*D
    float* qm   = h    + (size_t)N * D;           // N*D
    float* kmat = qm   + (size_t)N * D;           // N*D
    int*   cnt  = (int*)(kmat + (size_t)N * D);   // N
    int*   cols = cnt + N;                        // N*CAP

    phase1_kernel<<<N / 4, 256, 0, stream>>>(x, adj, W, b, scale,
                                             Wq, bq, scale_q, Wk, bk, scale_k,
                                             h, qm, kmat, cnt, cols);
    gather_kernel<<<N / 4, 256, 0, stream>>>(qm, kmat, h, cnt, cols,
                                             att_bias, att_scale, out);
}

// Round 6
// 800.035 us; speedup vs baseline: 1.0643x; 1.0643x over previous
//
#include <hip/hip_runtime.h>
#include <math.h>

#define N   12288
#define D   64
#define CAP 96   // max neighbors/row; Binomial(12288,0.002) mean 24.6, P(>=96) ~ 1e-30

typedef unsigned int uint4n __attribute__((ext_vector_type(4)));

__device__ __forceinline__ float wave_sum(float v) {
    #pragma unroll
    for (int m = 32; m >= 1; m >>= 1) v += __shfl_xor(v, m, 64);
    return v;
}
__device__ __forceinline__ float sigmoidf(float a) { return 1.0f / (1.0f + __expf(-a)); }

// K1: one wave per row: h = LL(x) kept in registers, then q (negated time) and k
// computed straight from register h. One dispatch for all three linears.
__global__ __launch_bounds__(256) void linear_kernel(
        const float* __restrict__ x,
        const float* __restrict__ W,  const float* __restrict__ b,  const float* __restrict__ scale,
        const float* __restrict__ Wq, const float* __restrict__ bq, const float* __restrict__ scale_q,
        const float* __restrict__ Wk, const float* __restrict__ bk, const float* __restrict__ scale_k,
        float* __restrict__ h, float* __restrict__ qm, float* __restrict__ kmat) {
    __shared__ float Wl [D * (D + 1)];   // +1 pad: 2-way bank alias (free)
    __shared__ float Wql[D * (D + 1)];
    __shared__ float Wkl[D * (D + 1)];

    const int tid  = threadIdx.x;
    const int lane = tid & 63;
    const int w    = tid >> 6;
    const int row  = blockIdx.x * 4 + w;

    for (int idx = tid; idx < D * D; idx += 256) {
        int d = idx >> 6, kk = idx & 63;
        Wl [d * (D + 1) + kk] = W [idx];
        Wql[d * (D + 1) + kk] = Wq[idx];
        Wkl[d * (D + 1) + kk] = Wk[idx];
    }
    __syncthreads();

    // ---- h = lorentz_linear(x)[row], kept in registers
    float hvv;
    {
        float xv  = x[row * D + lane];
        float acc = b[lane];
        const float* wr = &Wl[lane * (D + 1)];
        #pragma unroll
        for (int kk = 0; kk < D; ++kk)
            acc = fmaf(__shfl(xv, kk, 64), wr[kk], acc);
        float h0   = __shfl(acc, 0, 64);
        float time = __expf(scale[0]) * sigmoidf(h0) + 1.1f;
        float sq   = fmaxf(wave_sum((lane == 0) ? 0.0f : acc * acc), 1e-8f);
        float r    = sqrtf((time * time - 1.0f) / sq);
        hvv = (lane == 0) ? time : acc * r;
        h[row * D + lane] = hvv;
    }

    // ---- q (negated time) and k from register h, shared shuffle broadcast
    {
        float accq = bq[lane], acck = bk[lane];
        const float* wq = &Wql[lane * (D + 1)];
        const float* wk = &Wkl[lane * (D + 1)];
        #pragma unroll
        for (int kk = 0; kk < D; ++kk) {
            float xk = __shfl(hvv, kk, 64);
            accq = fmaf(xk, wq[kk], accq);
            acck = fmaf(xk, wk[kk], acck);
        }
        {
            float h0   = __shfl(accq, 0, 64);
            float time = __expf(scale_q[0]) * sigmoidf(h0) + 1.1f;
            float sq   = fmaxf(wave_sum((lane == 0) ? 0.0f : accq * accq), 1e-8f);
            float r    = sqrtf((time * time - 1.0f) / sq);
            qm[row * D + lane] = (lane == 0) ? -time : accq * r;
        }
        {
            float h0   = __shfl(acck, 0, 64);
            float time = __expf(scale_k[0]) * sigmoidf(h0) + 1.1f;
            float sq   = fmaxf(wave_sum((lane == 0) ? 0.0f : acck * acck), 1e-8f);
            float r    = sqrtf((time * time - 1.0f) / sq);
            kmat[row * D + lane] = (lane == 0) ? time : acck * r;
        }
    }
}

// K2: block `row` streams adj[row,:] (48 KB, 256 threads, 12 coalesced iters),
// compacts nonzero cols to LDS, then 4 waves gather sigmoid-weighted h rows
// and normalize. Neighbor lists never touch global memory.
__global__ __launch_bounds__(256) void adj_gather_kernel(
        const uint4n* __restrict__ adj4,
        const float* __restrict__ qm,
        const float* __restrict__ kmat,
        const float* __restrict__ h,
        const float* __restrict__ att_bias_p,
        const float* __restrict__ att_scale_p,
        float* __restrict__ out) {
    __shared__ int scols[CAP];
    __shared__ int scnt;
    __shared__ float sacc[4][D];

    int tid  = threadIdx.x;
    int row  = blockIdx.x;
    if (tid == 0) scnt = 0;
    __syncthreads();

    const uint4n* rowp = adj4 + (size_t)row * (N / 4);
    #pragma unroll
    for (int it = 0; it < (N / 4) / 256; ++it) {
        int t = it * 256 + tid;
        uint4n v = __builtin_nontemporal_load(&rowp[t]);
        if ((v.x | v.y | v.z | v.w) != 0u) {
            unsigned e[4] = {v.x, v.y, v.z, v.w};
            #pragma unroll
            for (int c = 0; c < 4; ++c) {
                if (e[c] != 0u) {
                    int pos = atomicAdd(&scnt, 1);   // LDS atomic
                    if (pos < CAP) scols[pos] = t * 4 + c;
                }
            }
        }
    }
    __syncthreads();

    int m = scnt; if (m > CAP) m = CAP;
    int lane = tid & 63;
    int w    = tid >> 6;

    float qv        = qm[row * D + lane];
    float bias      = att_bias_p[0];
    float inv_scale = 1.0f / att_scale_p[0];

    float acc = 0.0f;
    for (int n = w; n < m; n += 4) {
        int j = scols[n];                                  // wave-uniform broadcast
        float dot = wave_sum(qv * kmat[j * D + lane]);
        float att = sigmoidf(fmaf(2.0f + 2.0f * dot, inv_scale, bias));
        acc = fmaf(att, h[j * D + lane], acc);
    }
    sacc[w][lane] = acc;
    __syncthreads();

    if (w == 0) {
        float total = sacc[0][lane] + sacc[1][lane] + sacc[2][lane] + sacc[3][lane];
        float contrib = (lane == 0) ? -total * total : total * total;
        float inner   = wave_sum(contrib);
        float denorm  = sqrtf(fmaxf(fabsf(inner), 1e-8f));
        out[row * D + lane] = total / denorm;
    }
}

extern "C" void kernel_launch(void* const* d_in, const int* in_sizes, int n_in,
                              void* d_out, int out_size, void* d_ws, size_t ws_size,
                              hipStream_t stream) {
    const float*  x         = (const float*)d_in[0];
    const uint4n* adj       = (const uint4n*)d_in[1];
    const float*  W         = (const float*)d_in[2];
    const float*  b         = (const float*)d_in[3];
    const float*  scale     = (const float*)d_in[4];
    const float*  Wq        = (const float*)d_in[5];
    const float*  bq        = (const float*)d_in[6];
    const float*  scale_q   = (const float*)d_in[7];
    const float*  Wk        = (const float*)d_in[8];
    const float*  bk        = (const float*)d_in[9];
    const float*  scale_k   = (const float*)d_in[10];
    const float*  att_bias  = (const float*)d_in[11];
    const float*  att_scale = (const float*)d_in[12];
    float* out = (float*)d_out;

    float* h    = (float*)d_ws;           // N*D
    float* qm   = h  + (size_t)N * D;     // N*D
    float* kmat = qm + (size_t)N * D;     // N*D

    linear_kernel<<<N / 4, 256, 0, stream>>>(x, W, b, scale,
                                             Wq, bq, scale_q, Wk, bk, scale_k,
                                             h, qm, kmat);
    adj_gather_kernel<<<N, 256, 0, stream>>>(adj, qm, kmat, h,
                                             att_bias, att_scale, out);
}

// Round 7
// 785.841 us; speedup vs baseline: 1.0836x; 1.0181x over previous
//
#include <hip/hip_runtime.h>
#include <math.h>

#define N   12288
#define D   64
#define CAP 96   // max neighbors/row; Binomial(12288,0.002) mean 24.6, P(>=96) ~ 1e-30
#define ITS ((N / 4) / 256)   // 12 uint4 loads per thread per row

typedef unsigned int uint4n __attribute__((ext_vector_type(4)));

__device__ __forceinline__ float wave_sum(float v) {
    #pragma unroll
    for (int m = 32; m >= 1; m >>= 1) v += __shfl_xor(v, m, 64);
    return v;
}
__device__ __forceinline__ float sigmoidf(float a) { return 1.0f / (1.0f + __expf(-a)); }

// K1: one wave per row: h = LL(x) kept in registers, then q (negated time) and k
// computed straight from register h. One dispatch for all three linears.
__global__ __launch_bounds__(256) void linear_kernel(
        const float* __restrict__ x,
        const float* __restrict__ W,  const float* __restrict__ b,  const float* __restrict__ scale,
        const float* __restrict__ Wq, const float* __restrict__ bq, const float* __restrict__ scale_q,
        const float* __restrict__ Wk, const float* __restrict__ bk, const float* __restrict__ scale_k,
        float* __restrict__ h, float* __restrict__ qm, float* __restrict__ kmat) {
    __shared__ float Wl [D * (D + 1)];   // +1 pad: 2-way bank alias (free)
    __shared__ float Wql[D * (D + 1)];
    __shared__ float Wkl[D * (D + 1)];

    const int tid  = threadIdx.x;
    const int lane = tid & 63;
    const int w    = tid >> 6;
    const int row  = blockIdx.x * 4 + w;

    for (int idx = tid; idx < D * D; idx += 256) {
        int d = idx >> 6, kk = idx & 63;
        Wl [d * (D + 1) + kk] = W [idx];
        Wql[d * (D + 1) + kk] = Wq[idx];
        Wkl[d * (D + 1) + kk] = Wk[idx];
    }
    __syncthreads();

    float hvv;
    {
        float xv  = x[row * D + lane];
        float acc = b[lane];
        const float* wr = &Wl[lane * (D + 1)];
        #pragma unroll
        for (int kk = 0; kk < D; ++kk)
            acc = fmaf(__shfl(xv, kk, 64), wr[kk], acc);
        float h0   = __shfl(acc, 0, 64);
        float time = __expf(scale[0]) * sigmoidf(h0) + 1.1f;
        float sq   = fmaxf(wave_sum((lane == 0) ? 0.0f : acc * acc), 1e-8f);
        float r    = sqrtf((time * time - 1.0f) / sq);
        hvv = (lane == 0) ? time : acc * r;
        h[row * D + lane] = hvv;
    }

    {
        float accq = bq[lane], acck = bk[lane];
        const float* wq = &Wql[lane * (D + 1)];
        const float* wk = &Wkl[lane * (D + 1)];
        #pragma unroll
        for (int kk = 0; kk < D; ++kk) {
            float xk = __shfl(hvv, kk, 64);
            accq = fmaf(xk, wq[kk], accq);
            acck = fmaf(xk, wk[kk], acck);
        }
        {
            float h0   = __shfl(accq, 0, 64);
            float time = __expf(scale_q[0]) * sigmoidf(h0) + 1.1f;
            float sq   = fmaxf(wave_sum((lane == 0) ? 0.0f : accq * accq), 1e-8f);
            float r    = sqrtf((time * time - 1.0f) / sq);
            qm[row * D + lane] = (lane == 0) ? -time : accq * r;
        }
        {
            float h0   = __shfl(acck, 0, 64);
            float time = __expf(scale_k[0]) * sigmoidf(h0) + 1.1f;
            float sq   = fmaxf(wave_sum((lane == 0) ? 0.0f : acck * acck), 1e-8f);
            float r    = sqrtf((time * time - 1.0f) / sq);
            kmat[row * D + lane] = (lane == 0) ? time : acck * r;
        }
    }
}

// K2: block `row` streams adj[row,:] (48 KB) with ALL 12 16B NT loads issued
// back-to-back into registers (max MLP), then compacts nonzero cols to LDS and
// gathers sigmoid-weighted h rows. Lists never touch global memory.
__global__ __launch_bounds__(256) void adj_gather_kernel(
        const uint4n* __restrict__ adj4,
        const float* __restrict__ qm,
        const float* __restrict__ kmat,
        const float* __restrict__ h,
        const float* __restrict__ att_bias_p,
        const float* __restrict__ att_scale_p,
        float* __restrict__ out) {
    __shared__ int scols[CAP];
    __shared__ int scnt;
    __shared__ float sacc[4][D];

    int tid  = threadIdx.x;
    int row  = blockIdx.x;
    int lane = tid & 63;
    int w    = tid >> 6;
    if (tid == 0) scnt = 0;

    // issue all 12 streaming loads before anything that waits on them
    const uint4n* rowp = adj4 + (size_t)row * (N / 4);
    uint4n vv[ITS];
    #pragma unroll
    for (int it = 0; it < ITS; ++it)
        vv[it] = __builtin_nontemporal_load(&rowp[it * 256 + tid]);

    float qv        = qm[row * D + lane];   // overlaps with stream
    float bias      = att_bias_p[0];
    float inv_scale = 1.0f / att_scale_p[0];
    __syncthreads();   // scnt=0 visible (loads above are independent of LDS)

    #pragma unroll
    for (int it = 0; it < ITS; ++it) {
        uint4n v = vv[it];
        if ((v.x | v.y | v.z | v.w) != 0u) {
            int t = it * 256 + tid;
            unsigned e[4] = {v.x, v.y, v.z, v.w};
            #pragma unroll
            for (int c = 0; c < 4; ++c) {
                if (e[c] != 0u) {
                    int pos = atomicAdd(&scnt, 1);   // LDS atomic, rare (~25/row)
                    if (pos < CAP) scols[pos] = t * 4 + c;
                }
            }
        }
    }
    __syncthreads();

    int m = scnt; if (m > CAP) m = CAP;

    float acc = 0.0f;
    for (int n = w; n < m; n += 4) {
        int j = scols[n];                                  // wave-uniform broadcast
        float dot = wave_sum(qv * kmat[j * D + lane]);
        float att = sigmoidf(fmaf(2.0f + 2.0f * dot, inv_scale, bias));
        acc = fmaf(att, h[j * D + lane], acc);
    }
    sacc[w][lane] = acc;
    __syncthreads();

    if (w == 0) {
        float total = sacc[0][lane] + sacc[1][lane] + sacc[2][lane] + sacc[3][lane];
        float contrib = (lane == 0) ? -total * total : total * total;
        float inner   = wave_sum(contrib);
        float denorm  = sqrtf(fmaxf(fabsf(inner), 1e-8f));
        out[row * D + lane] = total / denorm;
    }
}

extern "C" void kernel_launch(void* const* d_in, const int* in_sizes, int n_in,
                              void* d_out, int out_size, void* d_ws, size_t ws_size,
                              hipStream_t stream) {
    const float*  x         = (const float*)d_in[0];
    const uint4n* adj       = (const uint4n*)d_in[1];
    const float*  W         = (const float*)d_in[2];
    const float*  b         = (const float*)d_in[3];
    const float*  scale     = (const float*)d_in[4];
    const float*  Wq        = (const float*)d_in[5];
    const float*  bq        = (const float*)d_in[6];
    const float*  scale_q   = (const float*)d_in[7];
    const float*  Wk        = (const float*)d_in[8];
    const float*  bk        = (const float*)d_in[9];
    const float*  scale_k   = (const float*)d_in[10];
    const float*  att_bias  = (const float*)d_in[11];
    const float*  att_scale = (const float*)d_in[12];
    float* out = (float*)d_out;

    float* h    = (float*)d_ws;           // N*D
    float* qm   = h  + (size_t)N * D;     // N*D
    float* kmat = qm + (size_t)N * D;     // N*D

    linear_kernel<<<N / 4, 256, 0, stream>>>(x, W, b, scale,
                                             Wq, bq, scale_q, Wk, bk, scale_k,
                                             h, qm, kmat);
    adj_gather_kernel<<<N, 256, 0, stream>>>(adj, qm, kmat, h,
                                             att_bias, att_scale, out);
}